// Round 4
// baseline (113.316 us; speedup 1.0000x reference)
//
#include <hip/hip_runtime.h>

// STU layer: out[b,t,e] = sum_{k,d} phi[t,k] * C[b,t,k,d] * W[k,e,d],
//            C = cumsum_t(phi[t,k] * x[b,t,d])
// Fused: out = A @ WT^T (M=16384, Kdim=4096, N=256); the A-tile
// (A[bt, d*16+k] = phi[t,k]*C[b,t,k,d]) is built in LDS from 16-step cumsum
// chains seeded by chunk-prefix states U; x/U chain inputs are prefetched
// into registers two phases ahead (T14 issue-early/consume-late).
//   WT[e, d*16+k] = W[k,e,d]
// B=4, T=4096, D=256, K=16, chunk CH=16 (256 chunks/batch).

typedef __bf16 bf16x8 __attribute__((ext_vector_type(8)));
typedef float  f32x4  __attribute__((ext_vector_type(4)));
typedef unsigned short u16;

__device__ static inline u16 f2bf(float f) {          // RNE f32->bf16
    unsigned int u = __float_as_uint(f);
    u = (u + 0x7fffu + ((u >> 16) & 1u)) >> 16;
    return (u16)u;
}

__device__ static inline void gload16(const void* g, void* l) {
    __builtin_amdgcn_global_load_lds((const __attribute__((address_space(1))) void*)g,
                                     (__attribute__((address_space(3))) void*)l, 16, 0, 0);
}

// ---------------- k0: WT[e][d*16+k] = bf16(W[k][e][d]) ----------------
__global__ __launch_bounds__(256) void k0_wt(const float* __restrict__ W, u16* __restrict__ WT) {
    const int e = blockIdx.x, d = threadIdx.x;
    union { u16 u[16]; uint4 v[2]; } ob;
#pragma unroll
    for (int k = 0; k < 16; ++k)
        ob.u[k] = f2bf(W[((size_t)k * 256 + e) * 256 + d]);
    uint4* dst = (uint4*)(WT + (size_t)e * 4096 + d * 16);
    dst[0] = ob.v[0]; dst[1] = ob.v[1];
}

// ---------------- k1: chunk sums U[b,c,d,k] = sum_{s in 16-chunk} phi*x ----------------
__global__ __launch_bounds__(256) void k1_sums(const float* __restrict__ x,
                                               const float* __restrict__ phi,
                                               float* __restrict__ U) {
    __shared__ float phis[256];
    const int tid = threadIdx.x;
    const int b = blockIdx.x, c = blockIdx.y;
    const int t0 = c * 16;
    phis[tid] = phi[t0 * 16 + tid];
    __syncthreads();
    float acc[16];
#pragma unroll
    for (int k = 0; k < 16; ++k) acc[k] = 0.f;
    for (int s = 0; s < 16; ++s) {
        const float xv = x[(size_t)((b << 12) + t0 + s) * 256 + tid];
        union { float f[16]; float4 v[4]; } pv;
#pragma unroll
        for (int j = 0; j < 4; ++j) pv.v[j] = *(const float4*)&phis[s * 16 + j * 4];
#pragma unroll
        for (int k = 0; k < 16; ++k) acc[k] = fmaf(pv.f[k], xv, acc[k]);
    }
    float4* Up = (float4*)(U + ((size_t)((b * 256 + c) * 256 + tid)) * 16);
    union { float f[16]; float4 v[4]; } ov;
#pragma unroll
    for (int k = 0; k < 16; ++k) ov.f[k] = acc[k];
#pragma unroll
    for (int j = 0; j < 4; ++j) Up[j] = ov.v[j];
}

// ---------------- k2: exclusive scan of U over c (in place), 256 chunks ----------------
// 256 blocks x 64 threads so the scan spreads across all CUs.
__global__ __launch_bounds__(64) void k2_scan(float* __restrict__ U) {
    const int b = blockIdx.x;                       // grid (4,64)
    const int dk = blockIdx.y * 64 + threadIdx.x;   // (d*16+k)
    float* base = U + (size_t)b * 1048576 + dk;
    float runv = 0.f;
    for (int g = 0; g < 16; ++g) {
        float v[16];
#pragma unroll
        for (int j = 0; j < 16; ++j) v[j] = base[(size_t)(g * 16 + j) * 4096];
#pragma unroll
        for (int j = 0; j < 16; ++j) {
            const float t = v[j];
            base[(size_t)(g * 16 + j) * 4096] = runv;
            runv += t;
        }
    }
}

// ---------------- k4: fused A-build + GEMM, K-split=2 via atomics ----------------
// BM=64, BN=256, BK=64; 512 threads = 8 waves. Waves 0-3: build A-tile
// (one 16-step cumsum chain per lane, x/U prefetched 2 phases ahead into
// registers). Waves 4-7: stage B via global_load_lds. Double-buffered LDS
// (A 2x8KB, B 2x32KB = 80KB), one barrier per K-step, K-loop unrolled x2
// so prefetch regsets have static names.
__global__ __launch_bounds__(512, 4) void k4_fused(const float* __restrict__ x,
                                                   const float* __restrict__ phi,
                                                   const float* __restrict__ U,
                                                   const u16* __restrict__ BT,
                                                   float* __restrict__ C) {
    __shared__ __align__(16) char smem[81920];   // A[2][8192] @0, B[2][32768] @16384
    const int tid = threadIdx.x;
    const int m0 = blockIdx.x * 64;              // global row base (bt)
    const int ks = blockIdx.y;                   // kdim half
    const int b  = m0 >> 12, t0 = m0 & 4095, c0 = t0 >> 4;
    const int w = tid >> 6, l = tid & 63;
    const int wm = (w >> 2) * 32, wn = (w & 3) * 64;
    const int lg = l >> 4, lr = l & 15;
    f32x4 acc[2][4] = {};

    // chain-lane constants (waves 0-3): chain = (chunk=w, d-local=lg, k=lr)
    const int dl = lg, kl = lr;
    const int cb = (dl * 16 + kl) * 2;           // A-tile column byte
    float p[16];
    if (w < 4) {
#pragma unroll
        for (int s = 0; s < 16; ++s) p[s] = phi[(t0 + w * 16 + s) * 16 + kl];
    }
    const char* Bb = (const char*)BT;
    const int tl = tid & 255;

    auto stageB = [&](int kt, int buf) {         // waves 4-7: 8 x gload16 each
        const int kofs = ks * 4096 + kt * 128;
#pragma unroll
        for (int c = 0; c < 8; ++c) {
            const int row = c * 32 + (tl >> 3);
            gload16(Bb + (size_t)row * 8192 + kofs + (((tl & 7) * 16) ^ ((row & 7) << 4)),
                    smem + 16384 + buf * 32768 + c * 4096 + tl * 16);
        }
    };
    auto issue = [&](float (&xr)[16], float& us, int kt) {   // prefetch x + U seed
        const int d = ks * 128 + kt * 4 + dl;
        const float* xp = x + (size_t)(m0 + w * 16) * 256 + d;
#pragma unroll
        for (int s = 0; s < 16; ++s) xr[s] = xp[(size_t)s * 256];
        us = U[(((size_t)(b * 256 + c0 + w)) * 256 + d) * 16 + kl];
    };
    auto chains = [&](const float (&xr)[16], float us, int buf) {
        float run = us;
        char* Ab = smem + buf * 8192 + (w * 16) * 128;   // rows w*16..w*16+15
#pragma unroll
        for (int s = 0; s < 16; ++s) {
            run = fmaf(p[s], xr[s], run);
            *(__bf16*)(Ab + s * 128 + (cb ^ ((s & 7) << 4))) = (__bf16)(p[s] * run);
        }
    };
    auto mfma_phase = [&](int buf) {
        const char* Abase = smem + buf * 8192;
        const char* Bbase = smem + 16384 + buf * 32768;
#pragma unroll
        for (int kk = 0; kk < 2; ++kk) {
            const int kb = kk * 64 + lg * 16;
            bf16x8 af[2], bfv[4];
#pragma unroll
            for (int mi = 0; mi < 2; ++mi) {
                const int r = wm + mi * 16 + lr;
                af[mi] = *(const bf16x8*)(Abase + r * 128 + (kb ^ ((r & 7) << 4)));
            }
#pragma unroll
            for (int ni = 0; ni < 4; ++ni) {
                const int n = wn + ni * 16 + lr;
                bfv[ni] = *(const bf16x8*)(Bbase + n * 128 + (kb ^ ((n & 7) << 4)));
            }
#pragma unroll
            for (int mi = 0; mi < 2; ++mi)
#pragma unroll
                for (int ni = 0; ni < 4; ++ni)
                    acc[mi][ni] = __builtin_amdgcn_mfma_f32_16x16x32_bf16(af[mi], bfv[ni], acc[mi][ni], 0, 0, 0);
        }
    };

    // prologue: fill buffer 0 (tile 0); prefetch x/U for tiles 0 and 1
    float xA[16], xB[16], uA, uB;
    if (w < 4) {
        issue(xA, uA, 0); issue(xB, uB, 1);
        chains(xA, uA, 0);
    } else {
        stageB(0, 0);
    }
    __syncthreads();

    for (int it = 0; it < 16; ++it) {
        const int kt0 = 2 * it;
        // even step: build tile kt0+1 into buf1, prefetch tile kt0+2 into xA
        if (w < 4) {
            if (kt0 + 2 < 32) issue(xA, uA, kt0 + 2);
            chains(xB, uB, 1);
        } else {
            stageB(kt0 + 1, 1);
        }
        mfma_phase(0);
        __syncthreads();
        // odd step: build tile kt0+2 into buf0, prefetch tile kt0+3 into xB
        const int kt1 = kt0 + 1;
        if (kt1 + 1 < 32) {
            if (w < 4) {
                if (kt1 + 2 < 32) issue(xB, uB, kt1 + 2);
                chains(xA, uA, 0);
            } else {
                stageB(kt1 + 1, 0);
            }
        }
        mfma_phase(1);
        __syncthreads();
    }

    // epilogue: two contributions per out element (ks=0/1), commutative f32 adds
#pragma unroll
    for (int mi = 0; mi < 2; ++mi)
#pragma unroll
        for (int ni = 0; ni < 4; ++ni)
#pragma unroll
            for (int r = 0; r < 4; ++r) {
                const int row = m0 + wm + mi * 16 + lg * 4 + r;
                const int col = wn + ni * 16 + lr;
                unsafeAtomicAdd(&C[(size_t)row * 256 + col], acc[mi][ni][r]);
            }
}

extern "C" void kernel_launch(void* const* d_in, const int* in_sizes, int n_in,
                              void* d_out, int out_size, void* d_ws, size_t ws_size,
                              hipStream_t stream) {
    const float* x   = (const float*)d_in[0];   // (4,4096,256)
    const float* W   = (const float*)d_in[1];   // (16,256,256)
    const float* phi = (const float*)d_in[2];   // (4096,16)
    float* out = (float*)d_out;                 // (4,4096,256) f32

    char* ws = (char*)d_ws;
    u16*   WT = (u16*)ws;                       // 2 MB
    float* U  = (float*)(ws + (2u << 20));      // 16 MB

    k0_wt  <<<256, 256, 0, stream>>>(W, WT);
    k1_sums<<<dim3(4, 256), 256, 0, stream>>>(x, phi, U);
    k2_scan<<<dim3(4, 64), 64, 0, stream>>>(U);
    hipMemsetAsync(d_out, 0, (size_t)out_size * sizeof(float), stream);
    k4_fused<<<dim3(256, 2), 512, 0, stream>>>(x, phi, U, WT, out);
}

// Round 5
// 102.961 us; speedup vs baseline: 1.1006x; 1.1006x over previous
//
#include <hip/hip_runtime.h>

// STU layer: out[b,t,e] = sum_{k,d} phi[t,k] * C[b,t,k,d] * W[k,e,d],
//            C = cumsum_t(phi[t,k] * x[b,t,d])
// Fused: out = A @ WT^T (M=16384, Kdim=4096, N=256); the A-tile
// (A[bt, d*16+k] = phi[t,k]*C[b,t,k,d]) is built in LDS from cumsum chains
// seeded by chunk-prefix states U. All 8 waves build: 2 lanes per chain
// (halves joined via shfl_xor 32). x loads issued before the MFMA phase and
// consumed after it (T14 within-phase split).
//   WT[e, d*16+k] = W[k,e,d]
// B=4, T=4096, D=256, K=16, chunk CH=16 (256 chunks/batch).

typedef __bf16 bf16x8 __attribute__((ext_vector_type(8)));
typedef float  f32x4  __attribute__((ext_vector_type(4)));
typedef unsigned short u16;

__device__ static inline u16 f2bf(float f) {          // RNE f32->bf16
    unsigned int u = __float_as_uint(f);
    u = (u + 0x7fffu + ((u >> 16) & 1u)) >> 16;
    return (u16)u;
}

__device__ static inline void gload16(const void* g, void* l) {
    __builtin_amdgcn_global_load_lds((const __attribute__((address_space(1))) void*)g,
                                     (__attribute__((address_space(3))) void*)l, 16, 0, 0);
}

// ---------------- k0: WT[e][d*16+k] = bf16(W[k][e][d]) ----------------
__global__ __launch_bounds__(256) void k0_wt(const float* __restrict__ W, u16* __restrict__ WT) {
    const int e = blockIdx.x, d = threadIdx.x;
    union { u16 u[16]; uint4 v[2]; } ob;
#pragma unroll
    for (int k = 0; k < 16; ++k)
        ob.u[k] = f2bf(W[((size_t)k * 256 + e) * 256 + d]);
    uint4* dst = (uint4*)(WT + (size_t)e * 4096 + d * 16);
    dst[0] = ob.v[0]; dst[1] = ob.v[1];
}

// ---------------- k1: chunk sums U[b,c,d,k] = sum_{s in 16-chunk} phi*x ----------------
__global__ __launch_bounds__(256) void k1_sums(const float* __restrict__ x,
                                               const float* __restrict__ phi,
                                               float* __restrict__ U) {
    __shared__ float phis[256];
    const int tid = threadIdx.x;
    const int b = blockIdx.x, c = blockIdx.y;
    const int t0 = c * 16;
    phis[tid] = phi[t0 * 16 + tid];
    __syncthreads();
    float acc[16];
#pragma unroll
    for (int k = 0; k < 16; ++k) acc[k] = 0.f;
    for (int s = 0; s < 16; ++s) {
        const float xv = x[(size_t)((b << 12) + t0 + s) * 256 + tid];
        union { float f[16]; float4 v[4]; } pv;
#pragma unroll
        for (int j = 0; j < 4; ++j) pv.v[j] = *(const float4*)&phis[s * 16 + j * 4];
#pragma unroll
        for (int k = 0; k < 16; ++k) acc[k] = fmaf(pv.f[k], xv, acc[k]);
    }
    float4* Up = (float4*)(U + ((size_t)((b * 256 + c) * 256 + tid)) * 16);
    union { float f[16]; float4 v[4]; } ov;
#pragma unroll
    for (int k = 0; k < 16; ++k) ov.f[k] = acc[k];
#pragma unroll
    for (int j = 0; j < 4; ++j) Up[j] = ov.v[j];
}

// ---------------- k2: exclusive scan of U over c (in place), 256 chunks ----------------
__global__ __launch_bounds__(64) void k2_scan(float* __restrict__ U) {
    const int b = blockIdx.x;                       // grid (4,64)
    const int dk = blockIdx.y * 64 + threadIdx.x;   // (d*16+k)
    float* base = U + (size_t)b * 1048576 + dk;
    float runv = 0.f;
    for (int g = 0; g < 16; ++g) {
        float v[16];
#pragma unroll
        for (int j = 0; j < 16; ++j) v[j] = base[(size_t)(g * 16 + j) * 4096];
#pragma unroll
        for (int j = 0; j < 16; ++j) {
            const float t = v[j];
            base[(size_t)(g * 16 + j) * 4096] = runv;
            runv += t;
        }
    }
}

// ---------------- k4: fused A-build + GEMM, K-split=2 via atomics ----------------
// BM=64, BN=256, BK=64; 512 threads = 8 waves. All waves: build (pair-split
// chains, 2 lanes/chain) + stage B (4 gload16/lane) + MFMA.
// LDS: A 2x8KB @0, B 2x32KB @16384 = 80KB -> 2 blocks/CU.
__global__ __launch_bounds__(512, 4) void k4_fused(const float* __restrict__ x,
                                                   const float* __restrict__ phi,
                                                   const float* __restrict__ U,
                                                   const u16* __restrict__ BT,
                                                   float* __restrict__ C) {
    __shared__ __align__(16) char smem[81920];
    const int tid = threadIdx.x;
    const int m0 = blockIdx.x * 64;              // global row base (bt)
    const int ks = blockIdx.y;                   // kdim half
    const int b  = m0 >> 12, t0 = m0 & 4095, c0 = t0 >> 4;
    const int w = tid >> 6, l = tid & 63;
    const int wm = (w >> 2) * 32, wn = (w & 3) * 64;
    const int lg = l >> 4, lr = l & 15;
    f32x4 acc[2][4] = {};

    // chain mapping: chain=(ch,dl,kl), 2 lanes/chain (sh = s-half)
    const int ch = w & 3, khi = w >> 2;
    const int klo = l & 7, dl = (l >> 3) & 3, sh = l >> 5;
    const int kl = khi * 8 + klo;
    const int row0 = ch * 16 + sh * 8;           // tile-local row base of half-chain
    const int colb = (dl * 16 + kl) * 2;

    float p[8];
#pragma unroll
    for (int s = 0; s < 8; ++s) p[s] = phi[(t0 + row0 + s) * 16 + kl];

    const char* Bb = (const char*)BT;
    float xr[8], useed;

    auto bload = [&](int kt) {                   // issue chain inputs (regs)
        const int d = ks * 128 + kt * 4 + dl;
        const float* xp = x + (size_t)(m0 + row0) * 256 + d;
#pragma unroll
        for (int s = 0; s < 8; ++s) xr[s] = xp[(size_t)s * 256];
        useed = U[(((size_t)(b * 256 + c0 + ch)) * 256 + d) * 16 + kl];
    };
    auto stageB = [&](int kt, int buf) {         // all waves: 4 gload16 each
        const int kofs = ks * 4096 + kt * 128;
#pragma unroll
        for (int c = 0; c < 4; ++c) {
            const int row = c * 64 + (tid >> 3);
            gload16(Bb + (size_t)row * 8192 + kofs + (((tid & 7) * 16) ^ ((row & 7) << 4)),
                    smem + 16384 + buf * 32768 + c * 8192 + tid * 16);
        }
    };
    auto bcomp = [&](int buf) {                  // consume xr/useed -> A-tile
        float run = sh ? 0.f : useed;
        float ap[8];
#pragma unroll
        for (int s = 0; s < 8; ++s) { run = fmaf(p[s], xr[s], run); ap[s] = run; }
        const float cross = __shfl_xor(run, 32, 64);
        const float base = sh ? cross : 0.f;
        char* Ab = smem + buf * 8192 + row0 * 128;
#pragma unroll
        for (int s = 0; s < 8; ++s)              // (row&7)==s -> swz = s<<4
            *(__bf16*)(Ab + s * 128 + (colb ^ (s << 4))) = (__bf16)(p[s] * (ap[s] + base));
    };
    auto mfma_phase = [&](int buf) {
        const char* Abase = smem + buf * 8192;
        const char* Bbase = smem + 16384 + buf * 32768;
#pragma unroll
        for (int kk = 0; kk < 2; ++kk) {
            const int kb = kk * 64 + lg * 16;
            bf16x8 af[2], bfv[4];
#pragma unroll
            for (int mi = 0; mi < 2; ++mi) {
                const int r = wm + mi * 16 + lr;
                af[mi] = *(const bf16x8*)(Abase + r * 128 + (kb ^ ((r & 7) << 4)));
            }
#pragma unroll
            for (int ni = 0; ni < 4; ++ni) {
                const int n = wn + ni * 16 + lr;
                bfv[ni] = *(const bf16x8*)(Bbase + n * 128 + (kb ^ ((n & 7) << 4)));
            }
#pragma unroll
            for (int mi = 0; mi < 2; ++mi)
#pragma unroll
                for (int ni = 0; ni < 4; ++ni)
                    acc[mi][ni] = __builtin_amdgcn_mfma_f32_16x16x32_bf16(af[mi], bfv[ni], acc[mi][ni], 0, 0, 0);
        }
    };

    // prologue: tile 0
    bload(0); stageB(0, 0); bcomp(0);
    __syncthreads();

    for (int kt = 0; kt < 32; ++kt) {
        const int cur = kt & 1;
        if (kt < 31) {                 // issue next tile's inputs BEFORE MFMA
            bload(kt + 1);
            stageB(kt + 1, cur ^ 1);
        }
        mfma_phase(cur);
        if (kt < 31) bcomp(cur ^ 1);   // consume after MFMA (loads had time in flight)
        __syncthreads();
    }

    // epilogue: two contributions per out element (ks=0/1), commutative f32 adds
#pragma unroll
    for (int mi = 0; mi < 2; ++mi)
#pragma unroll
        for (int ni = 0; ni < 4; ++ni)
#pragma unroll
            for (int r = 0; r < 4; ++r) {
                const int row = m0 + wm + mi * 16 + lg * 4 + r;
                const int col = wn + ni * 16 + lr;
                unsafeAtomicAdd(&C[(size_t)row * 256 + col], acc[mi][ni][r]);
            }
}

extern "C" void kernel_launch(void* const* d_in, const int* in_sizes, int n_in,
                              void* d_out, int out_size, void* d_ws, size_t ws_size,
                              hipStream_t stream) {
    const float* x   = (const float*)d_in[0];   // (4,4096,256)
    const float* W   = (const float*)d_in[1];   // (16,256,256)
    const float* phi = (const float*)d_in[2];   // (4096,16)
    float* out = (float*)d_out;                 // (4,4096,256) f32

    char* ws = (char*)d_ws;
    u16*   WT = (u16*)ws;                       // 2 MB
    float* U  = (float*)(ws + (2u << 20));      // 16 MB

    k0_wt  <<<256, 256, 0, stream>>>(W, WT);
    k1_sums<<<dim3(4, 256), 256, 0, stream>>>(x, phi, U);
    k2_scan<<<dim3(4, 64), 64, 0, stream>>>(U);
    hipMemsetAsync(d_out, 0, (size_t)out_size * sizeof(float), stream);
    k4_fused<<<dim3(256, 2), 512, 0, stream>>>(x, phi, U, WT, out);
}